// Round 1
// baseline (574.949 us; speedup 1.0000x reference)
//
#include <hip/hip_runtime.h>

#define HSZ 32
#define SEQ 1024

__device__ __forceinline__ float fast_rcp(float v) { return __builtin_amdgcn_rcpf(v); }

// sigmoid(x) = 1/(1+exp(-x)); exp arg bounded (|g| <~ 10), saturation via rcp(inf)=0 is safe.
__device__ __forceinline__ float sigmoidf_(float v) {
    return fast_rcp(1.0f + __expf(-v));
}

__global__ __launch_bounds__(64, 2)
void lstm_attn_fused(const float* __restrict__ x,
                     const float* __restrict__ W_ih,
                     const float* __restrict__ W_hh,
                     const float* __restrict__ b_ih,
                     const float* __restrict__ b_hh,
                     const float* __restrict__ attn_w,
                     const float* __restrict__ fc1_w,
                     const float* __restrict__ fc1_b,
                     const float* __restrict__ fc2_w,
                     const float* __restrict__ fc2_b,
                     float* __restrict__ out)
{
    const int lane = threadIdx.x;        // 0..63
    const int b    = blockIdx.x;         // batch element
    const int row0 = lane;               // gate rows: 0..63   -> i (0..31), f (32..63)
    const int row1 = lane + 64;          // gate rows: 64..127 -> g (64..95), o (96..127)
    const bool low = lane < HSZ;
    const int unit = lane & (HSZ - 1);

    // ---- preload weights into registers (static indexing only) ----
    float w0[HSZ], w1[HSZ];
#pragma unroll
    for (int k = 0; k < HSZ; ++k) {
        w0[k] = W_hh[row0 * HSZ + k];
        w1[k] = W_hh[row1 * HSZ + k];
    }
    float wi0[3], wi1[3];
#pragma unroll
    for (int i = 0; i < 3; ++i) {
        wi0[i] = W_ih[row0 * 3 + i];
        wi1[i] = W_ih[row1 * 3 + i];
    }
    const float bias0 = b_ih[row0] + b_hh[row0];
    const float bias1 = b_ih[row1] + b_hh[row1];
    const float aw    = attn_w[unit];

    // v1 nonlinearity: low half -> tanh(g1) = 2*sigmoid(2*g1)-1 ; high half -> sigmoid(g1)
    const float nsS = low ? 2.0f : 1.0f;   // input scale
    const float nsA = low ? 2.0f : 1.0f;   // output scale
    const float nsB = low ? -1.0f : 0.0f;  // output offset

    __shared__ float hsh[HSZ];
    if (low) hsh[lane] = 0.0f;
    __syncthreads();

    float c = 0.0f, h = 0.0f;
    float Pacc = 0.0f, lacc = 0.0f;   // online softmax-weighted pooling (no max needed: score <= ~5.7)

    const float* __restrict__ xb = x + (size_t)b * SEQ * 3;

    for (int s = 0; s < SEQ; ++s) {
        const float x0 = xb[s * 3 + 0];
        const float x1 = xb[s * 3 + 1];
        const float x2 = xb[s * 3 + 2];

        // input projection + bias
        float g0a = fmaf(wi0[0], x0, fmaf(wi0[1], x1, fmaf(wi0[2], x2, bias0)));
        float g1a = fmaf(wi1[0], x0, fmaf(wi1[1], x1, fmaf(wi1[2], x2, bias1)));
        float g0b = 0.0f, g1b = 0.0f;

        // recurrent matvec: g += W_hh[row,:] * h  (h broadcast from LDS)
#pragma unroll
        for (int k = 0; k < HSZ; k += 2) {
            const float hk0 = hsh[k];
            const float hk1 = hsh[k + 1];
            g0a = fmaf(w0[k],     hk0, g0a);
            g0b = fmaf(w0[k + 1], hk1, g0b);
            g1a = fmaf(w1[k],     hk0, g1a);
            g1b = fmaf(w1[k + 1], hk1, g1b);
        }
        const float g0 = g0a + g0b;
        const float g1 = g1a + g1b;

        // gate nonlinearities: v0 = sigmoid (i or f); v1 = tanh (low) / sigmoid (high)
        const float v0 = sigmoidf_(g0);
        const float v1 = fmaf(nsA, sigmoidf_(nsS * g1), nsB);

        // swap halves so every lane has i,f,g,o of its unit
        const float u0 = __shfl_xor(v0, 32);
        const float u1 = __shfl_xor(v1, 32);
        const float i_ = low ? v0 : u0;
        const float f_ = low ? u0 : v0;
        const float gg = low ? v1 : u1;
        const float o_ = low ? u1 : v1;

        c = fmaf(f_, c, i_ * gg);
        const float tc = fmaf(2.0f, sigmoidf_(2.0f * c), -1.0f);  // tanh(c)
        h = o_ * tc;

        __syncthreads();
        if (low) hsh[lane] = h;
        __syncthreads();

        // attention score for this step: relu(h . attn_w), reduced over the 32 units
        float p = h * aw;
        p += __shfl_xor(p, 1);
        p += __shfl_xor(p, 2);
        p += __shfl_xor(p, 4);
        p += __shfl_xor(p, 8);
        p += __shfl_xor(p, 16);
        p = fmaxf(p, 0.0f);

        const float w = __expf(p);       // bounded by exp(~5.7) ~ 290, fp32-safe over 1024 terms
        lacc += w;
        Pacc = fmaf(w, h, Pacc);
    }

    // ---- epilogue: pooled -> fc1(relu) -> fc2 ----
    __syncthreads();
    if (low) hsh[lane] = Pacc / lacc;     // pooled[unit]
    __syncthreads();

    __shared__ float h1sh[16];
    if (lane < 16) {
        float acc = fc1_b[lane];
#pragma unroll
        for (int k = 0; k < HSZ; ++k)
            acc = fmaf(fc1_w[lane * HSZ + k], hsh[k], acc);
        h1sh[lane] = fmaxf(acc, 0.0f);
    }
    __syncthreads();
    if (lane < 2) {
        float acc = fc2_b[lane];
#pragma unroll
        for (int j = 0; j < 16; ++j)
            acc = fmaf(fc2_w[lane * 16 + j], h1sh[j], acc);
        out[b * 2 + lane] = acc;
    }
}

extern "C" void kernel_launch(void* const* d_in, const int* in_sizes, int n_in,
                              void* d_out, int out_size, void* d_ws, size_t ws_size,
                              hipStream_t stream) {
    const float* x      = (const float*)d_in[0];
    const float* W_ih   = (const float*)d_in[1];
    const float* W_hh   = (const float*)d_in[2];
    const float* b_ih   = (const float*)d_in[3];
    const float* b_hh   = (const float*)d_in[4];
    const float* attn_w = (const float*)d_in[5];
    const float* fc1_w  = (const float*)d_in[6];
    const float* fc1_b  = (const float*)d_in[7];
    const float* fc2_w  = (const float*)d_in[8];
    const float* fc2_b  = (const float*)d_in[9];

    const int B = in_sizes[0] / (SEQ * 3);   // 2048

    lstm_attn_fused<<<dim3(B), dim3(64), 0, stream>>>(
        x, W_ih, W_hh, b_ih, b_hh, attn_w, fc1_w, fc1_b, fc2_w, fc2_b,
        (float*)d_out);
}

// Round 3
// 482.906 us; speedup vs baseline: 1.1906x; 1.1906x over previous
//
#include <hip/hip_runtime.h>

#define HSZ 32
#define SEQ 1024

__device__ __forceinline__ float fast_rcp(float v) { return __builtin_amdgcn_rcpf(v); }

// sigmoid(x) = 1/(1+exp(-x)); exp arg bounded (|g| <~ 12), rcp(inf)=0 saturation is safe.
__device__ __forceinline__ float sigmoidf_(float v) {
    return fast_rcp(1.0f + __expf(-v));
}

__global__ __launch_bounds__(64, 2)
void lstm_attn_fused(const float* __restrict__ x,
                     const float* __restrict__ W_ih,
                     const float* __restrict__ W_hh,
                     const float* __restrict__ b_ih,
                     const float* __restrict__ b_hh,
                     const float* __restrict__ attn_w,
                     const float* __restrict__ fc1_w,
                     const float* __restrict__ fc1_b,
                     const float* __restrict__ fc2_w,
                     const float* __restrict__ fc2_b,
                     float* __restrict__ out)
{
    const int lane = threadIdx.x;        // 0..63
    const int b    = blockIdx.x;         // batch element
    const int row0 = lane;               // rows 0..63  : i (lanes 0..31), f (lanes 32..63)
    const int row1 = lane + 64;          // rows 64..127: g (lanes 0..31), o (lanes 32..63)
    const bool low = lane < HSZ;

    // ---- preload weights into registers ----
    float w0[HSZ], w1[HSZ];
#pragma unroll
    for (int k = 0; k < HSZ; ++k) {
        w0[k] = W_hh[row0 * HSZ + k];
        w1[k] = W_hh[row1 * HSZ + k];
    }
    float wi0x = W_ih[row0 * 3 + 0], wi0y = W_ih[row0 * 3 + 1], wi0z = W_ih[row0 * 3 + 2];
    float wi1x = W_ih[row1 * 3 + 0], wi1y = W_ih[row1 * 3 + 1], wi1z = W_ih[row1 * 3 + 2];
    float bias0 = b_ih[row0] + b_hh[row0];
    float bias1 = b_ih[row1] + b_hh[row1];
    float aw    = attn_w[lane & (HSZ - 1)];

    // Pin loop-invariants into VGPRs: asm defs can't be rematerialized, so the
    // allocator must keep them live instead of re-gathering from L1 every step
    // (round-1 counters: VGPR_Count=56 proved W was reloaded per step).
#pragma unroll
    for (int k = 0; k < HSZ; ++k) {
        asm volatile("" : "+v"(w0[k]), "+v"(w1[k]));
    }
    asm volatile("" : "+v"(wi0x), "+v"(wi0y), "+v"(wi0z));
    asm volatile("" : "+v"(wi1x), "+v"(wi1y), "+v"(wi1z));
    asm volatile("" : "+v"(bias0), "+v"(bias1), "+v"(aw));

    // v1 nonlinearity: low half -> tanh(g1) = 2*sigmoid(2*g1)-1 ; high half -> sigmoid(g1)
    const float nsS = low ? 2.0f : 1.0f;
    const float nsA = low ? 2.0f : 1.0f;
    const float nsB = low ? -1.0f : 0.0f;

    __shared__ float hsh[HSZ];
    if (low) hsh[lane] = 0.0f;
    __syncthreads();

    float c = 0.0f, h = 0.0f;
    float Pacc = 0.0f, lacc = 0.0f;   // online softmax pooling (scores bounded ~5.7 -> no max tracking)

    const float4* __restrict__ xv = (const float4*)(x + (size_t)b * SEQ * 3);

    auto step = [&](float x0, float x1, float x2) {
        float g0a = fmaf(wi0x, x0, fmaf(wi0y, x1, fmaf(wi0z, x2, bias0)));
        float g1a = fmaf(wi1x, x0, fmaf(wi1y, x1, fmaf(wi1z, x2, bias1)));
        float g0b = 0.0f, g1b = 0.0f;

        // recurrent matvec: h broadcast from LDS (known-good round-1 path)
#pragma unroll
        for (int k = 0; k < HSZ; k += 2) {
            const float hk0 = hsh[k];
            const float hk1 = hsh[k + 1];
            g0a = fmaf(w0[k],     hk0, g0a);
            g0b = fmaf(w0[k + 1], hk1, g0b);
            g1a = fmaf(w1[k],     hk0, g1a);
            g1b = fmaf(w1[k + 1], hk1, g1b);
        }
        const float g0 = g0a + g0b;
        const float g1 = g1a + g1b;

        const float v0 = sigmoidf_(g0);                       // i (low) / f (high)
        const float v1 = fmaf(nsA, sigmoidf_(nsS * g1), nsB); // tanh g (low) / o (high)

        const float u0 = __shfl_xor(v0, 32);
        const float u1 = __shfl_xor(v1, 32);
        const float i_ = low ? v0 : u0;
        const float f_ = low ? u0 : v0;
        const float gg = low ? v1 : u1;
        const float o_ = low ? u1 : v1;

        c = fmaf(f_, c, i_ * gg);
        const float tc = fmaf(2.0f, sigmoidf_(2.0f * c), -1.0f);  // tanh(c)
        h = o_ * tc;

        __syncthreads();
        if (low) hsh[lane] = h;
        __syncthreads();

        // attention score: relu(h . attn_w) reduced over 32 units (both halves identical)
        float p = h * aw;
        p += __shfl_xor(p, 1);
        p += __shfl_xor(p, 2);
        p += __shfl_xor(p, 4);
        p += __shfl_xor(p, 8);
        p += __shfl_xor(p, 16);
        p = fmaxf(p, 0.0f);

        const float w = __expf(p);       // bounded by exp(~5.7) ~ 290, fp32-safe over 1024 terms
        lacc += w;
        Pacc = fmaf(w, h, Pacc);
    };

    for (int s0 = 0; s0 < SEQ; s0 += 4) {
        const int fi = (s0 * 3) >> 2;           // float4 index
        const float4 xa = xv[fi + 0];
        const float4 xb = xv[fi + 1];
        const float4 xc = xv[fi + 2];
        step(xa.x, xa.y, xa.z);
        step(xa.w, xb.x, xb.y);
        step(xb.z, xb.w, xc.x);
        step(xc.y, xc.z, xc.w);
    }

    // ---- epilogue: pooled -> fc1(relu) -> fc2 (round-1 LDS path) ----
    __syncthreads();
    if (low) hsh[lane] = Pacc / lacc;     // pooled[unit]
    __syncthreads();

    __shared__ float h1sh[16];
    if (lane < 16) {
        float acc = fc1_b[lane];
#pragma unroll
        for (int k = 0; k < HSZ; ++k)
            acc = fmaf(fc1_w[lane * HSZ + k], hsh[k], acc);
        h1sh[lane] = fmaxf(acc, 0.0f);
    }
    __syncthreads();
    if (lane < 2) {
        float acc = fc2_b[lane];
#pragma unroll
        for (int j = 0; j < 16; ++j)
            acc = fmaf(fc2_w[lane * 16 + j], h1sh[j], acc);
        out[b * 2 + lane] = acc;
    }
}

extern "C" void kernel_launch(void* const* d_in, const int* in_sizes, int n_in,
                              void* d_out, int out_size, void* d_ws, size_t ws_size,
                              hipStream_t stream) {
    const float* x      = (const float*)d_in[0];
    const float* W_ih   = (const float*)d_in[1];
    const float* W_hh   = (const float*)d_in[2];
    const float* b_ih   = (const float*)d_in[3];
    const float* b_hh   = (const float*)d_in[4];
    const float* attn_w = (const float*)d_in[5];
    const float* fc1_w  = (const float*)d_in[6];
    const float* fc1_b  = (const float*)d_in[7];
    const float* fc2_w  = (const float*)d_in[8];
    const float* fc2_b  = (const float*)d_in[9];

    const int B = in_sizes[0] / (SEQ * 3);   // 2048

    lstm_attn_fused<<<dim3(B), dim3(64), 0, stream>>>(
        x, W_ih, W_hh, b_ih, b_hh, attn_w, fc1_w, fc1_b, fc2_w, fc2_b,
        (float*)d_out);
}